// Round 2
// baseline (116.051 us; speedup 1.0000x reference)
//
#include <hip/hip_runtime.h>

#define GQ   8192            // bs(32) * Gn(256)
#define WPB  2               // waves per block (2 consecutive groups share 128B lines)
#define SQRT5 2.23606797749978969f   // sqrt(1/T), folded into means so sim = dot/T

// 6-step wave64 sum via DPP (row_shr 1/2/4/8 + row_bcast 15/31) -> total in lane 63.
// VALU pipe only: no LDS, no barriers.
template<int CTRL>
__device__ __forceinline__ float dpp_add(float v) {
    int t = __builtin_amdgcn_update_dpp(0, __float_as_int(v), CTRL, 0xF, 0xF, true);
    return v + __int_as_float(t);
}
__device__ __forceinline__ float wave_sum64(float v) {
    v = dpp_add<0x111>(v);   // row_shr:1
    v = dpp_add<0x112>(v);   // row_shr:2
    v = dpp_add<0x114>(v);   // row_shr:4
    v = dpp_add<0x118>(v);   // row_shr:8  -> lane 15/31/47/63 hold row sums
    v = dpp_add<0x142>(v);   // row_bcast:15 -> lane 31, 63 accumulate
    v = dpp_add<0x143>(v);   // row_bcast:31 -> lane 63 = wave total
    return v;
}

// One wave per group. ZERO LDS, ZERO barriers:
//  - dup/u logic via 6-bit match-any ballots (idx in [0,40) fits 6 bits)
//  - bucket means via 16 uniform switch dispatches (readlane -> scalar branch)
//  - sim Gram matrix: per-lane outer products + DPP tree reduce (44 pairs)
//  - sims -> wave-uniform SGPRs via readlane(63); masked LSE computed uniformly
__global__ __launch_bounds__(64 * WPB, 6) void group_loss_kernel(
    const int*   __restrict__ labs,   // [G*16]
    const float* __restrict__ feats,  // [32,128,256,16]
    const int*   __restrict__ idxs,   // [G*16]
    const float* __restrict__ ctx,    // [128]
    float2* __restrict__ ws)          // [G] {gl*gv, gv}
{
    const int l  = threadIdx.x & 63;
    const int wu = threadIdx.x >> 6;
    const int blk = blockIdx.x;
    // XCD blk&7 owns contiguous groups [x*1024,(x+1)*1024); block = gn pair
    const int g  = ((blk & 7) << 10) | ((blk >> 3) << 1) | wu;
    const int b  = g >> 8;
    const int gn = g & 255;
    const long fbase = (long)b * (128 * 256 * 16) + (long)gn * 16;

    // ---- feature columns straight to registers (lane l -> channels l, l+64)
    const float* gp0 = feats + fbase + (long)l * 4096;
    const float* gp1 = gp0 + 64 * 4096;
    float4 A[4], B[4];
    #pragma unroll
    for (int q = 0; q < 4; ++q) A[q] = *(const float4*)(gp0 + q * 4);
    #pragma unroll
    for (int q = 0; q < 4; ++q) B[q] = *(const float4*)(gp1 + q * 4);
    const float cx0 = ctx[l], cx1 = ctx[l + 64];

    // ---- label/index logic: lanes 0..15 hold sample s=l ---------------------
    int myidx = -1, mylab = -2;
    if (l < 16) { myidx = idxs[g * 16 + l]; mylab = labs[g * 16 + l]; }

    // u = count of distinct seed indices: 6-bit match-any via ballots.
    // lanes>=16 have myidx=-1 -> pattern 63, unreachable by idx<=39; masked anyway.
    unsigned long long mm = ~0ull;
    #pragma unroll
    for (int bit = 0; bit < 6; ++bit) {
        const unsigned long long bb = __ballot((myidx >> bit) & 1);
        mm &= ((myidx >> bit) & 1) ? bb : ~bb;
    }
    const bool dup = (mm & ((1ull << l) - 1) & 0xFFFFull) != 0ull;
    const int u = __popcll(__ballot((l < 16) && !dup));

    const bool valid = l < u;                   // u<=16, lanes>=16 invalid
    const int bid = valid ? (mylab + 1) : 255;  // bucket 0 = bg(-1), 1..8 = fg

    int cnt[9];
    #pragma unroll
    for (int r = 0; r < 9; ++r) cnt[r] = __popcll(__ballot(bid == r));
    const bool has_bg = cnt[0] > 0;
    int fg_count = 0, pm = 0;
    #pragma unroll
    for (int r = 1; r < 9; ++r)
        if (cnt[r] > 0) { ++fg_count; pm |= 1 << r; }

    // ---- unpack features AFTER ballot logic (lets loads overlap the logic) --
    float fa[16], fb[16];
    #pragma unroll
    for (int q = 0; q < 4; ++q) {
        fa[4*q+0] = A[q].x; fa[4*q+1] = A[q].y; fa[4*q+2] = A[q].z; fa[4*q+3] = A[q].w;
        fb[4*q+0] = B[q].x; fb[4*q+1] = B[q].y; fb[4*q+2] = B[q].z; fb[4*q+3] = B[q].w;
    }

    // ---- bucket sums: 16 uniform dispatches (readlane -> scalar switch) ----
    float m0[9] = {0,0,0,0,0,0,0,0,0};
    float m1[9] = {0,0,0,0,0,0,0,0,0};
    #pragma unroll
    for (int s = 0; s < 16; ++s) {
        if (s < u) {                                          // uniform compare
            const int bs = __builtin_amdgcn_readlane(bid, s); // uniform 0..8
            switch (bs) {
                case 0: m0[0] += fa[s]; m1[0] += fb[s]; break;
                case 1: m0[1] += fa[s]; m1[1] += fb[s]; break;
                case 2: m0[2] += fa[s]; m1[2] += fb[s]; break;
                case 3: m0[3] += fa[s]; m1[3] += fb[s]; break;
                case 4: m0[4] += fa[s]; m1[4] += fb[s]; break;
                case 5: m0[5] += fa[s]; m1[5] += fb[s]; break;
                case 6: m0[6] += fa[s]; m1[6] += fb[s]; break;
                case 7: m0[7] += fa[s]; m1[7] += fb[s]; break;
                case 8: m0[8] += fa[s]; m1[8] += fb[s]; break;
            }
        }
    }
    // means scaled by sqrt(5) so pairwise products carry the 1/T=5 factor
    #pragma unroll
    for (int r = 0; r < 9; ++r) {
        const float sc = SQRT5 / (float)(cnt[r] > 0 ? cnt[r] : 1);
        m0[r] *= sc; m1[r] *= sc;
    }
    if (!has_bg) { m0[0] = cx0 * SQRT5; m1[0] = cx1 * SQRT5; }

    // ---- 44 pairs (i,j), 1<=i<=8, 0<=j<=i: Gram via DPP reduce -------------
    const int PI_[44] = {1,1, 2,2,2, 3,3,3,3, 4,4,4,4,4, 5,5,5,5,5,5,
                         6,6,6,6,6,6,6, 7,7,7,7,7,7,7,7, 8,8,8,8,8,8,8,8,8};
    const int PJ_[44] = {0,1, 0,1,2, 0,1,2,3, 0,1,2,3,4, 0,1,2,3,4,5,
                         0,1,2,3,4,5,6, 0,1,2,3,4,5,6,7, 0,1,2,3,4,5,6,7,8};
    float pv[44];
    #pragma unroll
    for (int k = 0; k < 44; ++k)
        pv[k] = m0[PI_[k]] * m0[PJ_[k]] + m1[PI_[k]] * m1[PJ_[k]];
    #pragma unroll
    for (int k = 0; k < 44; ++k) pv[k] = wave_sum64(pv[k]);

    // ---- sims -> wave-uniform scalars; mask absent rows/cols to -inf -------
    const int cm = pm | 1;                       // col 0 (bg/ctx) always valid
    int svi[44];                                 // uniform bits -> SGPRs
    #pragma unroll
    for (int k = 0; k < 44; ++k) {
        const int s = __builtin_amdgcn_readlane(__float_as_int(pv[k]), 63);
        const bool keep = (((cm >> PI_[k]) & 1) != 0) && (((cm >> PJ_[k]) & 1) != 0);
        svi[k] = keep ? s : 0xFF800000;          // -inf bits
    }
    const int OFF_[9] = {0, 0, 2, 5, 9, 14, 20, 27, 35};
    #define SK(i, j) __int_as_float(svi[((i) >= (j)) ? (OFF_[(i)] + (j)) : (OFF_[(j)] + (i))])

    // ---- masked logsumexp per present fg row, computed uniformly -----------
    float ssum = 0.0f;
    #pragma unroll
    for (int r = 1; r < 9; ++r) {
        if ((pm >> r) & 1) {                     // wave-uniform branch
            float vmax = SK(r, 0);
            #pragma unroll
            for (int j = 1; j < 9; ++j) vmax = fmaxf(vmax, SK(r, j));
            float se = 0.0f;
            #pragma unroll
            for (int j = 0; j < 9; ++j) se += __expf(SK(r, j) - vmax); // exp(-inf)=0
            ssum += vmax + __logf(se) - SK(r, r);
        }
    }

    if (l == 0) {
        float2 r;
        r.x = ssum / (float)(fg_count > 0 ? fg_count : 1);  // gl*gv
        r.y = (fg_count > 0) ? 1.0f : 0.0f;                 // gv
        ws[g] = r;
    }
    #undef SK
}

// Deterministic 8192 -> 1 reduction
__global__ __launch_bounds__(1024) void reduce_kernel(
    const float2* __restrict__ ws, float* __restrict__ out)
{
    __shared__ float sa[1024], sb[1024];
    const int t = threadIdx.x;
    float a = 0.0f, b2 = 0.0f;
    for (int g = t; g < GQ; g += 1024) {
        float2 v = ws[g];
        a += v.x; b2 += v.y;
    }
    sa[t] = a; sb[t] = b2;
    __syncthreads();
    for (int off = 512; off > 0; off >>= 1) {
        if (t < off) { sa[t] += sa[t + off]; sb[t] += sb[t + off]; }
        __syncthreads();
    }
    if (t == 0) out[0] = 0.1f * (sa[0] / sb[0]);
}

extern "C" void kernel_launch(void* const* d_in, const int* in_sizes, int n_in,
                              void* d_out, int out_size, void* d_ws, size_t ws_size,
                              hipStream_t stream) {
    const int*   labs  = (const int*)d_in[0];    // proposal_instance_mask
    const float* feats = (const float*)d_in[1];  // grouped_features
    const int*   idxs  = (const int*)d_in[2];    // grouped_indices
    const float* ctx   = (const float*)d_in[3];  // context_compen
    float* out = (float*)d_out;
    float2* ws = (float2*)d_ws;

    group_loss_kernel<<<GQ / WPB, 64 * WPB, 0, stream>>>(labs, feats, idxs, ctx, ws);
    reduce_kernel<<<1, 1024, 0, stream>>>(ws, out);
}

// Round 3
// 115.059 us; speedup vs baseline: 1.0086x; 1.0086x over previous
//
#include <hip/hip_runtime.h>

#define GQ    8192           // bs(32) * Gn(256)
#define BLKG  8              // groups per block (8 waves, 512 threads)
#define MROW  132            // LDS row stride in floats (128 + 4 pad: quad spread)
#define SQRT5 2.23606797749978969f   // sqrt(1/T), folded into means so sim = dot/T

// 6-step wave64 sum via DPP (row_shr 1/2/4/8 + row_bcast 15/31) -> total in lane 63.
template<int CTRL>
__device__ __forceinline__ float dpp_add(float v) {
    int t = __builtin_amdgcn_update_dpp(0, __float_as_int(v), CTRL, 0xF, 0xF, true);
    return v + __int_as_float(t);
}
__device__ __forceinline__ float wave_sum64(float v) {
    v = dpp_add<0x111>(v);   // row_shr:1
    v = dpp_add<0x112>(v);   // row_shr:2
    v = dpp_add<0x114>(v);   // row_shr:4
    v = dpp_add<0x118>(v);   // row_shr:8  -> lane 15/31/47/63 hold row sums
    v = dpp_add<0x142>(v);   // row_bcast:15 -> lane 31, 63 accumulate
    v = dpp_add<0x143>(v);   // row_bcast:31 -> lane 63 = wave total
    return v;
}

// Block = 8 waves = 8 consecutive groups (same batch b).
// Phase 1: cooperative COALESCED stage of [128 c][8 gn][16 s] (64 KB) into LDS —
//          per channel the block's 512 B are contiguous in HBM; every load
//          instruction is a sequential 1 KB burst (16 lines, vs 64 scattered).
// Phase 2: wave w = group g0+w; lane l = channels (l, l+64) read from LDS at
//          floor-rate (row stride 132 words -> quad (l+c)%8). Ballot label
//          logic + uniform bucket switch + DPP Gram + uniform masked LSE.
__global__ __launch_bounds__(64 * BLKG, 4) void group_loss_kernel(
    const int*   __restrict__ labs,   // [G*16]
    const float* __restrict__ feats,  // [32,128,256,16]
    const int*   __restrict__ idxs,   // [G*16]
    const float* __restrict__ ctx,    // [128]
    float2* __restrict__ ws)          // [G] {gl*gv, gv}
{
    __shared__ float SH[128 * MROW];            // 67584 B -> 2 blocks/CU

    const int l  = threadIdx.x & 63;
    const int w  = threadIdx.x >> 6;            // wave id = local group id
    const int g0 = blockIdx.x * BLKG;
    const int g  = g0 + w;
    const int b  = g0 >> 8;                     // 8 | 256 -> same b for the block
    const int gn0 = g0 & 255;

    // ---- label/index loads first (1 cache line each per wave) --------------
    int myidx = -1, mylab = -2;
    if (l < 16) { myidx = idxs[g * 16 + l]; mylab = labs[g * 16 + l]; }
    const float cx0 = ctx[l], cx1 = ctx[l + 64];

    // ---- phase 1: coalesced stage, 8 x 1KB bursts per wave ------------------
    {
        const int half = l >> 5;                // lanes 0-31 run A, 32-63 run B
        const int lo   = l & 31;
        const float* base = feats + (long)b * 524288 + (long)gn0 * 16;
        #pragma unroll
        for (int k = 0; k < 8; ++k) {
            const int c = k * 16 + w * 2 + half;         // channel 0..127, unique
            const float4 v = *(const float4*)(base + (long)c * 4096 + lo * 4);
            *(float4*)(SH + c * MROW + lo * 4) = v;
        }
    }
    __syncthreads();

    // ---- u = count of distinct seed indices: 6-bit match-any ballots -------
    unsigned long long mm = ~0ull;
    #pragma unroll
    for (int bit = 0; bit < 6; ++bit) {
        const unsigned long long bb = __ballot((myidx >> bit) & 1);
        mm &= ((myidx >> bit) & 1) ? bb : ~bb;
    }
    const bool dup = (mm & ((1ull << l) - 1) & 0xFFFFull) != 0ull;
    const int u = __popcll(__ballot((l < 16) && !dup));

    const bool valid = l < u;                   // u<=16, lanes>=16 invalid
    const int bid = valid ? (mylab + 1) : 255;  // bucket 0 = bg(-1), 1..8 = fg

    int cnt[9];
    #pragma unroll
    for (int r = 0; r < 9; ++r) cnt[r] = __popcll(__ballot(bid == r));
    const bool has_bg = cnt[0] > 0;
    int fg_count = 0, pm = 0;
    #pragma unroll
    for (int r = 1; r < 9; ++r)
        if (cnt[r] > 0) { ++fg_count; pm |= 1 << r; }

    // ---- phase 2: lane l = channels (l, l+64); 16 samples from LDS ---------
    float fa[16], fb[16];
    {
        const float* Ra = SH + l * MROW + w * 16;        // row l, group w's 16 s
        const float* Rb = SH + (l + 64) * MROW + w * 16;
        #pragma unroll
        for (int q = 0; q < 4; ++q) {
            const float4 x = *(const float4*)(Ra + 4 * q);
            const float4 y = *(const float4*)(Rb + 4 * q);
            fa[4*q+0] = x.x; fa[4*q+1] = x.y; fa[4*q+2] = x.z; fa[4*q+3] = x.w;
            fb[4*q+0] = y.x; fb[4*q+1] = y.y; fb[4*q+2] = y.z; fb[4*q+3] = y.w;
        }
    }

    // ---- bucket sums: 16 uniform dispatches (readlane -> scalar switch) ----
    float m0[9] = {0,0,0,0,0,0,0,0,0};
    float m1[9] = {0,0,0,0,0,0,0,0,0};
    #pragma unroll
    for (int s = 0; s < 16; ++s) {
        if (s < u) {                                          // uniform compare
            const int bs = __builtin_amdgcn_readlane(bid, s); // uniform 0..8
            switch (bs) {
                case 0: m0[0] += fa[s]; m1[0] += fb[s]; break;
                case 1: m0[1] += fa[s]; m1[1] += fb[s]; break;
                case 2: m0[2] += fa[s]; m1[2] += fb[s]; break;
                case 3: m0[3] += fa[s]; m1[3] += fb[s]; break;
                case 4: m0[4] += fa[s]; m1[4] += fb[s]; break;
                case 5: m0[5] += fa[s]; m1[5] += fb[s]; break;
                case 6: m0[6] += fa[s]; m1[6] += fb[s]; break;
                case 7: m0[7] += fa[s]; m1[7] += fb[s]; break;
                case 8: m0[8] += fa[s]; m1[8] += fb[s]; break;
            }
        }
    }
    // means scaled by sqrt(5) so pairwise products carry the 1/T=5 factor
    #pragma unroll
    for (int r = 0; r < 9; ++r) {
        const float sc = SQRT5 / (float)(cnt[r] > 0 ? cnt[r] : 1);
        m0[r] *= sc; m1[r] *= sc;
    }
    if (!has_bg) { m0[0] = cx0 * SQRT5; m1[0] = cx1 * SQRT5; }

    // ---- 44 pairs (i,j), 1<=i<=8, 0<=j<=i: Gram via DPP reduce -------------
    const int PI_[44] = {1,1, 2,2,2, 3,3,3,3, 4,4,4,4,4, 5,5,5,5,5,5,
                         6,6,6,6,6,6,6, 7,7,7,7,7,7,7,7, 8,8,8,8,8,8,8,8,8};
    const int PJ_[44] = {0,1, 0,1,2, 0,1,2,3, 0,1,2,3,4, 0,1,2,3,4,5,
                         0,1,2,3,4,5,6, 0,1,2,3,4,5,6,7, 0,1,2,3,4,5,6,7,8};
    const int cm = pm | 1;                       // col 0 (bg/ctx) always valid
    int svi[44];                                 // uniform bits (SGPR-class)
    #pragma unroll
    for (int k = 0; k < 44; ++k) {
        float pv = m0[PI_[k]] * m0[PJ_[k]] + m1[PI_[k]] * m1[PJ_[k]];
        pv = wave_sum64(pv);
        const int s = __builtin_amdgcn_readlane(__float_as_int(pv), 63);
        const bool keep = (((cm >> PI_[k]) & 1) != 0) && (((cm >> PJ_[k]) & 1) != 0);
        svi[k] = keep ? s : 0xFF800000;          // -inf bits
    }
    const int OFF_[9] = {0, 0, 2, 5, 9, 14, 20, 27, 35};
    #define SK(i, j) __int_as_float(svi[((i) >= (j)) ? (OFF_[(i)] + (j)) : (OFF_[(j)] + (i))])

    // ---- masked logsumexp per present fg row, computed uniformly -----------
    float ssum = 0.0f;
    #pragma unroll
    for (int r = 1; r < 9; ++r) {
        if ((pm >> r) & 1) {                     // wave-uniform branch
            float vmax = SK(r, 0);
            #pragma unroll
            for (int j = 1; j < 9; ++j) vmax = fmaxf(vmax, SK(r, j));
            float se = 0.0f;
            #pragma unroll
            for (int j = 0; j < 9; ++j) se += __expf(SK(r, j) - vmax); // exp(-inf)=0
            ssum += vmax + __logf(se) - SK(r, r);
        }
    }
    #undef SK

    if (l == 0) {
        float2 r;
        r.x = ssum / (float)(fg_count > 0 ? fg_count : 1);  // gl*gv
        r.y = (fg_count > 0) ? 1.0f : 0.0f;                 // gv
        ws[g] = r;
    }
}

// Deterministic 8192 -> 1 reduction
__global__ __launch_bounds__(1024) void reduce_kernel(
    const float2* __restrict__ ws, float* __restrict__ out)
{
    __shared__ float sa[1024], sb[1024];
    const int t = threadIdx.x;
    float a = 0.0f, b2 = 0.0f;
    for (int g = t; g < GQ; g += 1024) {
        float2 v = ws[g];
        a += v.x; b2 += v.y;
    }
    sa[t] = a; sb[t] = b2;
    __syncthreads();
    for (int off = 512; off > 0; off >>= 1) {
        if (t < off) { sa[t] += sa[t + off]; sb[t] += sb[t + off]; }
        __syncthreads();
    }
    if (t == 0) out[0] = 0.1f * (sa[0] / sb[0]);
}

extern "C" void kernel_launch(void* const* d_in, const int* in_sizes, int n_in,
                              void* d_out, int out_size, void* d_ws, size_t ws_size,
                              hipStream_t stream) {
    const int*   labs  = (const int*)d_in[0];    // proposal_instance_mask
    const float* feats = (const float*)d_in[1];  // grouped_features
    const int*   idxs  = (const int*)d_in[2];    // grouped_indices
    const float* ctx   = (const float*)d_in[3];  // context_compen
    float* out = (float*)d_out;
    float2* ws = (float2*)d_ws;

    group_loss_kernel<<<GQ / BLKG, 64 * BLKG, 0, stream>>>(labs, feats, idxs, ctx, ws);
    reduce_kernel<<<1, 1024, 0, stream>>>(ws, out);
}